// Round 2
// baseline (5939.997 us; speedup 1.0000x reference)
//
#include <hip/hip_runtime.h>
#include <hip/hip_bf16.h>
#include <math.h>

#define NN   50000
#define INF_ 64
#define HH   128
#define NSH  8
#define TT   8
#define EE   400000
#define CC   10

// ---------------- input projection: x = elu(x0 @ Wp.T + bp) ----------------
__global__ __launch_bounds__(256) void k_proj(const float* __restrict__ xo,
    const float* __restrict__ Wp, const float* __restrict__ bp, float* __restrict__ x)
{
    int tid = blockIdx.x * 256 + threadIdx.x;          // n*128 + j
    int n = tid >> 7, j = tid & 127;
    const float* xr = xo + n * INF_;
    const float* wr = Wp + j * INF_;
    float acc = bp[j];
    #pragma unroll
    for (int i = 0; i < INF_; ++i) acc = fmaf(xr[i], wr[i], acc);
    x[tid] = acc > 0.f ? acc : (expf(acc) - 1.f);
}

// --- h = x @ Wg.T (stored bf16); p1 = h.a1, p2 = h.a2 per head (fp32) -------
__global__ __launch_bounds__(128) void k_h(const float* __restrict__ x,
    const float* __restrict__ Wg, const float* __restrict__ a,
    __hip_bfloat16* __restrict__ h, float* __restrict__ p1, float* __restrict__ p2)
{
    int n = blockIdx.x, j = threadIdx.x;
    __shared__ float xs[HH];
    xs[j] = x[n * HH + j];
    __syncthreads();
    const float* wr = Wg + j * HH;
    float acc = 0.f;
    #pragma unroll 8
    for (int i = 0; i < HH; ++i) acc = fmaf(xs[i], wr[i], acc);
    h[n * HH + j] = __float2bfloat16(acc);
    int d = j & 15;
    float c1 = acc * a[d], c2 = acc * a[16 + d];
    #pragma unroll
    for (int off = 8; off; off >>= 1) {
        c1 += __shfl_xor(c1, off);
        c2 += __shfl_xor(c2, off);
    }
    if (d == 0) {
        int head = j >> 4;
        p1[n * NSH + head] = c1;
        p2[n * NSH + head] = c2;
    }
}

// ---- per-edge scores: ex[e,h] = exp(leakyrelu(p1[src]+p2[dst])), z += ex ---
__global__ __launch_bounds__(256) void k_scores(const int* __restrict__ ei_t,
    const float* __restrict__ p1, const float* __restrict__ p2,
    float* __restrict__ ex, float* __restrict__ z_t)
{
    int e = blockIdx.x * 256 + threadIdx.x;
    if (e >= EE) return;
    int src = ei_t[e], dst = ei_t[EE + e];
    const float4* P1 = (const float4*)(p1 + src * NSH);
    const float4* P2 = (const float4*)(p2 + dst * NSH);
    float4 a0 = P1[0], a1 = P1[1], b0 = P2[0], b1 = P2[1];
    float s[NSH] = {a0.x + b0.x, a0.y + b0.y, a0.z + b0.z, a0.w + b0.w,
                    a1.x + b1.x, a1.y + b1.y, a1.z + b1.z, a1.w + b1.w};
    float ev[NSH];
    #pragma unroll
    for (int k = 0; k < NSH; ++k) {
        float v = s[k];
        v = v > 0.f ? v : 0.2f * v;
        ev[k] = expf(v);
    }
    float4* EX = (float4*)(ex + e * NSH);
    EX[0] = make_float4(ev[0], ev[1], ev[2], ev[3]);
    EX[1] = make_float4(ev[4], ev[5], ev[6], ev[7]);
    float* zr = z_t + dst * NSH;
    #pragma unroll
    for (int k = 0; k < NSH; ++k) atomicAdd(&zr[k], ev[k]);
}

// ---- message pass: acc[dst,j] += (ex/z) * h[src,j] -------------------------
__global__ __launch_bounds__(256) void k_msg(const int* __restrict__ ei_t,
    const float* __restrict__ ex, const float* __restrict__ z_t,
    const __hip_bfloat16* __restrict__ h, float* __restrict__ acc)
{
    int idx = blockIdx.x * 256 + threadIdx.x;          // e*128 + j
    int j = idx & 127;
    int e = idx >> 7;
    int src = ei_t[e], dst = ei_t[EE + e];
    int head = j >> 4;
    float alpha = ex[e * NSH + head] / z_t[dst * NSH + head];
    float hv = __bfloat162float(h[src * HH + j]);
    atomicAdd(&acc[dst * HH + j], alpha * hv);
}

// ---- finalize: seq[t] = elu(LN(acc + x)) + pe[t]  (bf16) -------------------
__global__ __launch_bounds__(128) void k_final(const float* __restrict__ acc,
    const float* __restrict__ x, const float* __restrict__ g, const float* __restrict__ b,
    __hip_bfloat16* __restrict__ seq_t, int t)
{
    int n = blockIdx.x, j = threadIdx.x;
    float v = acc[n * HH + j] + x[n * HH + j];
    float s1 = v, s2 = v * v;
    #pragma unroll
    for (int off = 32; off; off >>= 1) { s1 += __shfl_xor(s1, off); s2 += __shfl_xor(s2, off); }
    __shared__ float r1[2], r2[2];
    if ((j & 63) == 0) { r1[j >> 6] = s1; r2[j >> 6] = s2; }
    __syncthreads();
    float sum = r1[0] + r1[1], sumsq = r2[0] + r2[1];
    float mu  = sum * (1.f / HH);
    float var = sumsq * (1.f / HH) - mu * mu;
    float y = (v - mu) * rsqrtf(var + 1e-5f) * g[j] + b[j];
    y = y > 0.f ? y : (expf(y) - 1.f);
    // pe[t, 2i] = sin(t*div_i), pe[t, 2i+1] = cos(t*div_i), div_i = exp(-2i*ln(1e4)/128)
    float div = expf((float)(j & ~1) * (-9.210340371976184f / 128.f));
    float ang = (float)t * div;
    y += (j & 1) ? cosf(ang) : sinf(ang);
    seq_t[n * HH + j] = __float2bfloat16(y);
}

// ---- temporal attention (only t = T-1 output needed) + LN + classifier ----
__global__ __launch_bounds__(128) void k_temporal(const __hip_bfloat16* __restrict__ seq,
    const float* __restrict__ Wqkv, const float* __restrict__ bqkv,
    const float* __restrict__ Wo, const float* __restrict__ bo,
    const float* __restrict__ g2, const float* __restrict__ b2,
    const float* __restrict__ Wc, const float* __restrict__ bc, float* __restrict__ out)
{
    int n = blockIdx.x, j = threadIdx.x;
    int head = j >> 5, d = j & 31;
    __shared__ float sp[TT][HH];
    #pragma unroll
    for (int t = 0; t < TT; ++t)
        sp[t][j] = __bfloat162float(seq[((size_t)t * NN + n) * HH + j]);
    __syncthreads();

    // qkv row mapping from reshape(T,N,4,96)->split: q: h*96+d, k: +32, v: +64
    int qrow = head * 96 + d;
    const float* wq = Wqkv + qrow * HH;
    const float* wk = Wqkv + (qrow + 32) * HH;
    const float* wv = Wqkv + (qrow + 64) * HH;

    float q = bqkv[qrow];
    #pragma unroll 8
    for (int i = 0; i < HH; ++i) q = fmaf(sp[7][i], wq[i], q);

    float kk[TT], vv[TT];
    float bk = bqkv[qrow + 32], bv = bqkv[qrow + 64];
    #pragma unroll
    for (int t = 0; t < TT; ++t) { kk[t] = bk; vv[t] = bv; }
    for (int i = 0; i < HH; ++i) {
        float wki = wk[i], wvi = wv[i];
        #pragma unroll
        for (int t = 0; t < TT; ++t) {
            kk[t] = fmaf(sp[t][i], wki, kk[t]);
            vv[t] = fmaf(sp[t][i], wvi, vv[t]);
        }
    }

    float sc[TT];
    #pragma unroll
    for (int t = 0; t < TT; ++t) {
        float p = q * kk[t];
        #pragma unroll
        for (int off = 16; off; off >>= 1) p += __shfl_xor(p, off);
        sc[t] = p * 0.17677669529663689f;
    }
    float mx = sc[0];
    #pragma unroll
    for (int t = 1; t < TT; ++t) mx = fmaxf(mx, sc[t]);
    float ssum = 0.f, al[TT];
    #pragma unroll
    for (int t = 0; t < TT; ++t) { al[t] = expf(sc[t] - mx); ssum += al[t]; }
    float inv = 1.f / ssum;
    float o = 0.f;
    #pragma unroll
    for (int t = 0; t < TT; ++t) o = fmaf(al[t] * inv, vv[t], o);

    __shared__ float osh[HH];
    osh[j] = o;
    __syncthreads();
    const float* wo = Wo + j * HH;
    float y = bo[j];
    #pragma unroll 8
    for (int i = 0; i < HH; ++i) y = fmaf(osh[i], wo[i], y);
    y += sp[7][j];

    float s1 = y, s2 = y * y;
    #pragma unroll
    for (int off = 32; off; off >>= 1) { s1 += __shfl_xor(s1, off); s2 += __shfl_xor(s2, off); }
    __shared__ float r1[2], r2[2];
    if ((j & 63) == 0) { r1[j >> 6] = s1; r2[j >> 6] = s2; }
    __syncthreads();
    float sum = r1[0] + r1[1], sumsq = r2[0] + r2[1];
    float mu  = sum * (1.f / HH);
    float var = sumsq * (1.f / HH) - mu * mu;
    float f = (y - mu) * rsqrtf(var + 1e-5f) * g2[j] + b2[j];
    f = f > 0.f ? f : (expf(f) - 1.f);

    __shared__ float fsh[HH];
    fsh[j] = f;
    __syncthreads();
    if (j < CC) {
        const float* wc = Wc + j * HH;
        float acc = bc[j];
        #pragma unroll 8
        for (int i = 0; i < HH; ++i) acc = fmaf(fsh[i], wc[i], acc);
        out[n * CC + j] = acc;
    }
}

extern "C" void kernel_launch(void* const* d_in, const int* in_sizes, int n_in,
                              void* d_out, int out_size, void* d_ws, size_t ws_size,
                              hipStream_t stream)
{
    const float* xo   = (const float*)d_in[0];
    const int*   ei   = (const int*)d_in[1];
    // d_in[2] node_masks: all-ones, unused by reference
    const float* Wp   = (const float*)d_in[3];
    const float* bp   = (const float*)d_in[4];
    const float* Wg   = (const float*)d_in[5];
    const float* a    = (const float*)d_in[6];
    const float* g1   = (const float*)d_in[7];
    const float* b1   = (const float*)d_in[8];
    const float* Wqkv = (const float*)d_in[9];
    const float* bqkv = (const float*)d_in[10];
    const float* Wo   = (const float*)d_in[11];
    const float* bo   = (const float*)d_in[12];
    const float* g2   = (const float*)d_in[13];
    const float* b2   = (const float*)d_in[14];
    const float* Wc   = (const float*)d_in[15];
    const float* bc   = (const float*)d_in[16];
    float* out = (float*)d_out;

    // workspace layout (float offsets)
    float* x    = (float*)d_ws;                              // N*H        = 6.4M
    float* p1   = x    + (size_t)NN * HH;                    // N*8        = 0.4M
    float* p2   = p1   + (size_t)NN * NSH;                   // N*8        = 0.4M
    float* z    = p2   + (size_t)NN * NSH;                   // T*N*8      = 3.2M
    float* ex   = z    + (size_t)TT * NN * NSH;              // E*8        = 3.2M
    float* acc  = ex   + (size_t)EE * NSH;                   // N*H        = 6.4M
    __hip_bfloat16* h   = (__hip_bfloat16*)(acc + (size_t)NN * HH);   // N*H bf16 (3.2M floats)
    __hip_bfloat16* seq = (__hip_bfloat16*)((float*)h + (size_t)NN * HH / 2); // T*N*H bf16 (25.6M floats)

    size_t need_floats = (size_t)NN * HH          // x
                       + (size_t)NN * NSH * 2     // p1,p2
                       + (size_t)TT * NN * NSH    // z
                       + (size_t)EE * NSH         // ex
                       + (size_t)NN * HH          // acc
                       + (size_t)NN * HH / 2      // h bf16
                       + (size_t)TT * NN * HH / 2;// seq bf16
    if (ws_size < need_floats * sizeof(float)) return;  // clean fail, not a GPU fault

    hipMemsetAsync(z, 0, (size_t)TT * NN * NSH * sizeof(float), stream);

    k_proj<<<NN * HH / 256, 256, 0, stream>>>(xo, Wp, bp, x);
    k_h   <<<NN, 128, 0, stream>>>(x, Wg, a, h, p1, p2);

    for (int t = 0; t < TT; ++t) {
        const int* eit = ei + (size_t)t * 2 * EE;
        float* zt = z + (size_t)t * NN * NSH;
        k_scores<<<(EE + 255) / 256, 256, 0, stream>>>(eit, p1, p2, ex, zt);
        hipMemsetAsync(acc, 0, (size_t)NN * HH * sizeof(float), stream);
        k_msg   <<<EE * HH / 256, 256, 0, stream>>>(eit, ex, zt, h, acc);
        k_final <<<NN, 128, 0, stream>>>(acc, x, g1, b1, seq + (size_t)t * NN * HH, t);
    }

    k_temporal<<<NN, 128, 0, stream>>>(seq, Wqkv, bqkv, Wo, bo, g2, b2, Wc, bc, out);
}

// Round 3
// 2266.764 us; speedup vs baseline: 2.6205x; 2.6205x over previous
//
#include <hip/hip_runtime.h>
#include <hip/hip_bf16.h>
#include <math.h>

#define NN   50000
#define INF_ 64
#define HH   128
#define NSH  8
#define TT   8
#define EE   400000
#define CC   10

typedef __attribute__((ext_vector_type(8))) short short8;
typedef __attribute__((ext_vector_type(4))) short short4v;
typedef __attribute__((ext_vector_type(4))) float f32x4;

__device__ __forceinline__ float b2f(unsigned short u){
    unsigned v = ((unsigned)u) << 16; float f; __builtin_memcpy(&f, &v, 4); return f;
}
__device__ __forceinline__ unsigned short f2b(float f){
    unsigned x; __builtin_memcpy(&x, &f, 4);
    x += 0x7fffu + ((x >> 16) & 1u);
    return (unsigned short)(x >> 16);
}

// ---------------- input projection: x = elu(x0 @ Wp.T + bp) ----------------
__global__ __launch_bounds__(256) void k_proj(const float* __restrict__ xo,
    const float* __restrict__ Wp, const float* __restrict__ bp, float* __restrict__ x)
{
    int tid = blockIdx.x * 256 + threadIdx.x;          // n*128 + j
    int n = tid >> 7, j = tid & 127;
    const float* xr = xo + n * INF_;
    const float* wr = Wp + j * INF_;
    float acc = bp[j];
    #pragma unroll
    for (int i = 0; i < INF_; ++i) acc = fmaf(xr[i], wr[i], acc);
    x[tid] = acc > 0.f ? acc : (expf(acc) - 1.f);
}

// --- h = x @ Wg.T (bf16); p1 = h.a1, p2 = h.a2 per head (fp32) --------------
__global__ __launch_bounds__(128) void k_h(const float* __restrict__ x,
    const float* __restrict__ Wg, const float* __restrict__ a,
    unsigned short* __restrict__ h, float* __restrict__ p1, float* __restrict__ p2)
{
    int n = blockIdx.x, j = threadIdx.x;
    __shared__ float xs[HH];
    xs[j] = x[n * HH + j];
    __syncthreads();
    const float* wr = Wg + j * HH;
    float acc = 0.f;
    #pragma unroll 8
    for (int i = 0; i < HH; ++i) acc = fmaf(xs[i], wr[i], acc);
    h[(size_t)n * HH + j] = f2b(acc);
    int d = j & 15;
    float c1 = acc * a[d], c2 = acc * a[16 + d];
    #pragma unroll
    for (int off = 8; off; off >>= 1) {
        c1 += __shfl_xor(c1, off);
        c2 += __shfl_xor(c2, off);
    }
    if (d == 0) {
        int head = j >> 4;
        p1[n * NSH + head] = c1;
        p2[n * NSH + head] = c2;
    }
}

// ---- degree histogram over all snapshots -----------------------------------
__global__ __launch_bounds__(256) void k_deg(const int* __restrict__ ei, int* __restrict__ deg)
{
    int e = blockIdx.x * 256 + threadIdx.x;
    int t = blockIdx.y;
    if (e >= EE) return;
    int dst = ei[(size_t)t * 2 * EE + EE + e];
    atomicAdd(&deg[t * NN + dst], 1);
}

// ---- exclusive scan per snapshot (one block of 1024 per t) ------------------
__global__ __launch_bounds__(1024) void k_scan(const int* __restrict__ deg,
    int* __restrict__ rowptr, int* __restrict__ cur)
{
    int t = blockIdx.x, tid = threadIdx.x;
    const int CH = (NN + 1023) / 1024;                  // 49
    __shared__ int sm[1024];
    const int* d = deg + (size_t)t * NN;
    int s = 0;
    for (int c = 0; c < CH; ++c) { int i = tid * CH + c; if (i < NN) s += d[i]; }
    sm[tid] = s;
    __syncthreads();
    for (int off = 1; off < 1024; off <<= 1) {
        int v = (tid >= off) ? sm[tid - off] : 0;
        __syncthreads();
        sm[tid] += v;
        __syncthreads();
    }
    int run = sm[tid] - s;                              // exclusive prefix
    int* rp = rowptr + (size_t)t * NN;
    int* cu = cur    + (size_t)t * NN;
    for (int c = 0; c < CH; ++c) {
        int i = tid * CH + c;
        if (i < NN) { rp[i] = run; cu[i] = run; run += d[i]; }
    }
}

// ---- scatter edges into dst-sorted order, computing exp(score) -------------
__global__ __launch_bounds__(256) void k_scatter(const int* __restrict__ ei_t,
    const float* __restrict__ p1, const float* __restrict__ p2,
    int* __restrict__ cur_t, int* __restrict__ esrc, float* __restrict__ exs)
{
    int e = blockIdx.x * 256 + threadIdx.x;
    if (e >= EE) return;
    int src = ei_t[e], dst = ei_t[EE + e];
    const float4* P1 = (const float4*)(p1 + src * NSH);
    const float4* P2 = (const float4*)(p2 + dst * NSH);
    float4 a0 = P1[0], a1 = P1[1], b0 = P2[0], b1 = P2[1];
    float s[NSH] = {a0.x + b0.x, a0.y + b0.y, a0.z + b0.z, a0.w + b0.w,
                    a1.x + b1.x, a1.y + b1.y, a1.z + b1.z, a1.w + b1.w};
    float ev[NSH];
    #pragma unroll
    for (int k = 0; k < NSH; ++k) {
        float v = s[k];
        v = v > 0.f ? v : 0.2f * v;
        ev[k] = expf(v);
    }
    int pos = atomicAdd(&cur_t[dst], 1);
    esrc[pos] = src;
    float4* EX = (float4*)(exs + (size_t)pos * NSH);
    EX[0] = make_float4(ev[0], ev[1], ev[2], ev[3]);
    EX[1] = make_float4(ev[4], ev[5], ev[6], ev[7]);
}

// ---- per-node GAT reduce + LN + elu + pe (fused) ----------------------------
__global__ __launch_bounds__(128) void k_gat_node(const int* __restrict__ rowptr_t,
    const int* __restrict__ deg_t, const int* __restrict__ esrc,
    const float* __restrict__ exs, const unsigned short* __restrict__ h,
    const float* __restrict__ x, const float* __restrict__ g, const float* __restrict__ b,
    unsigned short* __restrict__ seq_t, int t)
{
    int n = blockIdx.x, j = threadIdx.x, head = j >> 4;
    int start = rowptr_t[n], dg = deg_t[n];
    float z = 0.f;
    for (int ee = 0; ee < dg; ++ee) z += exs[(size_t)(start + ee) * NSH + head];
    float rz = dg > 0 ? 1.f / z : 0.f;
    float acc = 0.f;
    for (int ee = 0; ee < dg; ++ee) {
        int src = esrc[start + ee];
        float alpha = exs[(size_t)(start + ee) * NSH + head] * rz;
        acc = fmaf(alpha, b2f(h[(size_t)src * HH + j]), acc);
    }
    float v = acc + x[(size_t)n * HH + j];
    float s1 = v, s2 = v * v;
    #pragma unroll
    for (int off = 32; off; off >>= 1) { s1 += __shfl_xor(s1, off); s2 += __shfl_xor(s2, off); }
    __shared__ float r1[2], r2[2];
    if ((j & 63) == 0) { r1[j >> 6] = s1; r2[j >> 6] = s2; }
    __syncthreads();
    float sum = r1[0] + r1[1], sumsq = r2[0] + r2[1];
    float mu  = sum * (1.f / HH);
    float var = sumsq * (1.f / HH) - mu * mu;
    float y = (v - mu) * rsqrtf(var + 1e-5f) * g[j] + b[j];
    y = y > 0.f ? y : (expf(y) - 1.f);
    float div = expf((float)(j & ~1) * (-9.210340371976184f / 128.f));
    float ang = (float)t * div;
    y += (j & 1) ? cosf(ang) : sinf(ang);
    seq_t[(size_t)n * HH + j] = f2b(y);
}

// ---- fused temporal block: MFMA qkv -> attention -> MFMA Wo -> LN -> cls ---
#define LDS_A 0
#define LDS_B 34816
#define LDS_O 139264
#define LDS_Y 143616
#define LDS_R 152064

__global__ __launch_bounds__(256, 1) void k_temporal_mfma(
    const unsigned short* __restrict__ seq, const float* __restrict__ Wqkv,
    const float* __restrict__ bqkv, const float* __restrict__ Wo,
    const float* __restrict__ bo, const float* __restrict__ g2,
    const float* __restrict__ b2, const float* __restrict__ Wc,
    const float* __restrict__ bc, float* __restrict__ out)
{
    __shared__ __align__(16) char lds[152128];
    unsigned short* A_l = (unsigned short*)(lds + LDS_A);   // [128 rows][136] (seq tile, then Wo)
    unsigned short* B_l = (unsigned short*)(lds + LDS_B);   // [384 rows][136] (Wqkv, then C^T)
    unsigned short* C_l = B_l;                               // [384 cols][136], 128 rows used
    unsigned short* o_l = (unsigned short*)(lds + LDS_O);   // [16][136]
    float*          y_l = (float*)(lds + LDS_Y);             // [16][132]
    float*          red = (float*)(lds + LDS_R);             // partials

    int tid = threadIdx.x;
    int n0 = blockIdx.x * 16;

    // stage A: 16 nodes x 8 t of seq (bf16 passthrough); row r = ln*8 + t
    for (int w = tid; w < 128 * 32; w += 256) {
        int r = w >> 5, i4 = (w & 31) * 4;
        int t = r & 7, ln = r >> 3;
        *(short4v*)(A_l + r * 136 + i4) =
            *(const short4v*)(seq + ((size_t)t * NN + n0 + ln) * HH + i4);
    }
    // stage B: Wqkv fp32 -> bf16, row-major [384][128] (+pad)
    for (int w = tid; w < 384 * 32; w += 256) {
        int r = w >> 5, i4 = (w & 31) * 4;
        float4 v = *(const float4*)(Wqkv + r * HH + i4);
        short4v p;
        p[0] = (short)f2b(v.x); p[1] = (short)f2b(v.y);
        p[2] = (short)f2b(v.z); p[3] = (short)f2b(v.w);
        *(short4v*)(B_l + r * 136 + i4) = p;
    }
    __syncthreads();

    int wid = tid >> 6, lane = tid & 63, lm = lane & 15, kg = lane >> 4;

    // B fragments: 6 n-tiles per wave x 4 k-steps
    short8 bf[6][4];
    #pragma unroll
    for (int ntl = 0; ntl < 6; ++ntl)
        #pragma unroll
        for (int ks = 0; ks < 4; ++ks)
            bf[ntl][ks] = *(short8*)(B_l + ((wid * 6 + ntl) * 16 + lm) * 136 + ks * 32 + kg * 8);

    f32x4 acc[8][6];
    #pragma unroll
    for (int mt = 0; mt < 8; ++mt)
        #pragma unroll
        for (int ntl = 0; ntl < 6; ++ntl)
            acc[mt][ntl] = (f32x4){0.f, 0.f, 0.f, 0.f};

    #pragma unroll
    for (int mt = 0; mt < 8; ++mt) {
        short8 af[4];
        #pragma unroll
        for (int ks = 0; ks < 4; ++ks)
            af[ks] = *(short8*)(A_l + (mt * 16 + lm) * 136 + ks * 32 + kg * 8);
        #pragma unroll
        for (int ntl = 0; ntl < 6; ++ntl)
            #pragma unroll
            for (int ks = 0; ks < 4; ++ks)
                acc[mt][ntl] = __builtin_amdgcn_mfma_f32_16x16x32_bf16(
                    af[ks], bf[ntl][ks], acc[mt][ntl], 0, 0, 0);
    }
    __syncthreads();   // everyone done reading A_l/B_l

    // write C transposed bf16: C_l[col][row], row = mt*16 + kg*4 + reg, col = nt*16 + lm
    #pragma unroll
    for (int mt = 0; mt < 8; ++mt)
        #pragma unroll
        for (int ntl = 0; ntl < 6; ++ntl) {
            int col = (wid * 6 + ntl) * 16 + lm;
            int r0 = mt * 16 + kg * 4;
            unsigned p01 = (unsigned)f2b(acc[mt][ntl][0]) | ((unsigned)f2b(acc[mt][ntl][1]) << 16);
            unsigned p23 = (unsigned)f2b(acc[mt][ntl][2]) | ((unsigned)f2b(acc[mt][ntl][3]) << 16);
            *(unsigned*)(C_l + col * 136 + r0)     = p01;
            *(unsigned*)(C_l + col * 136 + r0 + 2) = p23;
        }
    __syncthreads();

    // attention per node (t=7 query only)
    int sub = tid >> 7, j = tid & 127, hh = j >> 5;
    int qcol = hh * 96 + (j & 31), kcol = qcol + 32, vcol = qcol + 64;
    float bq = bqkv[qcol], bk = bqkv[kcol], bv = bqkv[vcol];
    #pragma unroll
    for (int it = 0; it < 8; ++it) {
        int ln = it * 2 + sub;
        short8 kf = *(short8*)(C_l + kcol * 136 + ln * 8);
        short8 vf = *(short8*)(C_l + vcol * 136 + ln * 8);
        float qv = b2f(C_l[qcol * 136 + ln * 8 + 7]) + bq;
        float sc[8];
        #pragma unroll
        for (int t = 0; t < 8; ++t) {
            float p = qv * (b2f((unsigned short)kf[t]) + bk);
            #pragma unroll
            for (int off = 16; off; off >>= 1) p += __shfl_xor(p, off);
            sc[t] = p * 0.17677669529663689f;
        }
        float mx = sc[0];
        #pragma unroll
        for (int t = 1; t < 8; ++t) mx = fmaxf(mx, sc[t]);
        float se = 0.f;
        #pragma unroll
        for (int t = 0; t < 8; ++t) { sc[t] = expf(sc[t] - mx); se += sc[t]; }
        float inv = 1.f / se, ov = 0.f;
        #pragma unroll
        for (int t = 0; t < 8; ++t) ov = fmaf(sc[t] * inv, b2f((unsigned short)vf[t]) + bv, ov);
        o_l[ln * 136 + j] = f2b(ov);
    }
    __syncthreads();

    // stage Wo bf16 into A region (A is dead)
    for (int w = tid; w < 128 * 32; w += 256) {
        int r = w >> 5, i4 = (w & 31) * 4;
        float4 v = *(const float4*)(Wo + r * HH + i4);
        short4v p;
        p[0] = (short)f2b(v.x); p[1] = (short)f2b(v.y);
        p[2] = (short)f2b(v.z); p[3] = (short)f2b(v.w);
        *(short4v*)(A_l + r * 136 + i4) = p;
    }
    __syncthreads();

    // Wo GEMM: M=16 (nodes), N=128, K=128; wave handles 2 n-tiles
    short8 af2[4];
    #pragma unroll
    for (int ks = 0; ks < 4; ++ks)
        af2[ks] = *(short8*)(o_l + lm * 136 + ks * 32 + kg * 8);
    #pragma unroll
    for (int q2 = 0; q2 < 2; ++q2) {
        int col0 = (wid * 2 + q2) * 16;
        f32x4 yac = (f32x4){0.f, 0.f, 0.f, 0.f};
        #pragma unroll
        for (int ks = 0; ks < 4; ++ks)
            yac = __builtin_amdgcn_mfma_f32_16x16x32_bf16(
                af2[ks], *(short8*)(A_l + (col0 + lm) * 136 + ks * 32 + kg * 8), yac, 0, 0, 0);
        #pragma unroll
        for (int rg = 0; rg < 4; ++rg)
            y_l[(kg * 4 + rg) * 132 + col0 + lm] = yac[rg];
    }
    __syncthreads();

    // residual + LN + elu + classifier
    float* red1 = red;
    float* red2 = red + 4;
    for (int p = 0; p < 8; ++p) {
        int ln = p * 2 + sub;
        float y = y_l[ln * 132 + j] + bo[j]
                + b2f(seq[((size_t)7 * NN + n0 + ln) * HH + j]);
        float s1 = y, s2 = y * y;
        #pragma unroll
        for (int off = 32; off; off >>= 1) { s1 += __shfl_xor(s1, off); s2 += __shfl_xor(s2, off); }
        if ((j & 63) == 0) { red1[sub * 2 + (j >> 6)] = s1; red2[sub * 2 + (j >> 6)] = s2; }
        __syncthreads();
        float sum = red1[sub * 2] + red1[sub * 2 + 1];
        float sumsq = red2[sub * 2] + red2[sub * 2 + 1];
        float mu  = sum * (1.f / HH);
        float var = sumsq * (1.f / HH) - mu * mu;
        float f = (y - mu) * rsqrtf(var + 1e-5f) * g2[j] + b2[j];
        f = f > 0.f ? f : (expf(f) - 1.f);
        y_l[ln * 132 + j] = f;
        __syncthreads();
        if (j < CC) {
            float a = bc[j];
            const float* wc = Wc + j * HH;
            #pragma unroll 8
            for (int i = 0; i < HH; ++i) a = fmaf(wc[i], y_l[ln * 132 + i], a);
            out[(size_t)(n0 + ln) * CC + j] = a;
        }
        __syncthreads();
    }
}

extern "C" void kernel_launch(void* const* d_in, const int* in_sizes, int n_in,
                              void* d_out, int out_size, void* d_ws, size_t ws_size,
                              hipStream_t stream)
{
    const float* xo   = (const float*)d_in[0];
    const int*   ei   = (const int*)d_in[1];
    const float* Wp   = (const float*)d_in[3];
    const float* bp   = (const float*)d_in[4];
    const float* Wg   = (const float*)d_in[5];
    const float* a    = (const float*)d_in[6];
    const float* g1   = (const float*)d_in[7];
    const float* b1   = (const float*)d_in[8];
    const float* Wqkv = (const float*)d_in[9];
    const float* bqkv = (const float*)d_in[10];
    const float* Wo   = (const float*)d_in[11];
    const float* bo   = (const float*)d_in[12];
    const float* g2   = (const float*)d_in[13];
    const float* b2   = (const float*)d_in[14];
    const float* Wc   = (const float*)d_in[15];
    const float* bc   = (const float*)d_in[16];
    float* out = (float*)d_out;

    // workspace layout (byte offsets, all 16B-aligned)
    char* W = (char*)d_ws;
    float*          x      = (float*)(W + 0);                       // 25,600,000
    float*          p1     = (float*)(W + 25600000);                //  1,600,000
    float*          p2     = (float*)(W + 27200000);                //  1,600,000
    unsigned short* h      = (unsigned short*)(W + 28800000);       // 12,800,000
    unsigned short* seq    = (unsigned short*)(W + 41600000);       // 102,400,000
    int*            deg    = (int*)(W + 144000000);                 //  1,600,000
    int*            rowptr = (int*)(W + 145600000);                 //  1,600,000
    int*            cur    = (int*)(W + 147200000);                 //  1,600,000
    int*            esrc   = (int*)(W + 148800000);                 //  1,600,000
    float*          exs    = (float*)(W + 150400000);               // 12,800,000
    // total ~163.2 MB

    if (ws_size < (size_t)163200000) return;

    hipMemsetAsync(deg, 0, (size_t)TT * NN * sizeof(int), stream);

    k_proj<<<NN * HH / 256, 256, 0, stream>>>(xo, Wp, bp, x);
    k_h   <<<NN, 128, 0, stream>>>(x, Wg, a, h, p1, p2);
    k_deg <<<dim3((EE + 255) / 256, TT), 256, 0, stream>>>(ei, deg);
    k_scan<<<TT, 1024, 0, stream>>>(deg, rowptr, cur);

    for (int t = 0; t < TT; ++t) {
        const int* eit = ei + (size_t)t * 2 * EE;
        k_scatter <<<(EE + 255) / 256, 256, 0, stream>>>(eit, p1, p2,
                    cur + (size_t)t * NN, esrc, exs);
        k_gat_node<<<NN, 128, 0, stream>>>(rowptr + (size_t)t * NN,
                    deg + (size_t)t * NN, esrc, exs, h, x, g1, b1,
                    seq + (size_t)t * NN * HH, t);
    }

    k_temporal_mfma<<<NN / 16, 256, 0, stream>>>(seq, Wqkv, bqkv, Wo, bo,
                                                 g2, b2, Wc, bc, out);
}